// Round 18
// baseline (299.156 us; speedup 1.0000x reference)
//
#include <hip/hip_runtime.h>

typedef __attribute__((ext_vector_type(4))) float f32x4;
typedef __attribute__((ext_vector_type(16))) float f32x16;
typedef __attribute__((ext_vector_type(8))) short bf16x8;
typedef __attribute__((ext_vector_type(4))) unsigned u32x4;

#define DEV __device__ __forceinline__

DEV unsigned short f2bf(float f) {            // RTNE f32 -> bf16
  unsigned u = __float_as_uint(f);
  unsigned r = (u + 0x7FFFu + ((u >> 16) & 1u)) >> 16;
  return (unsigned short)r;
}
DEV float bf2f(unsigned short h) { return __uint_as_float(((unsigned)h) << 16); }

DEV unsigned cvtpk(float lo, float hi) {      // packed f32x2 -> bf16x2 (HW RTNE)
  unsigned r;
  asm("v_cvt_pk_bf16_f32 %0, %1, %2" : "=v"(r) : "v"(lo), "v"(hi));
  return r;
}
DEV bf16x8 frag4(unsigned a, unsigned b, unsigned c, unsigned d) {
  u32x4 u = {a, b, c, d};
  return __builtin_bit_cast(bf16x8, u);
}

typedef __attribute__((address_space(1))) void gas_t;
typedef __attribute__((address_space(3))) void las_t;
DEV void async16(void* lds, const void* g) {
  __builtin_amdgcn_global_load_lds((gas_t*)g, (las_t*)lds, 16, 0, 0);
}

// ------- fused prep: cast x -> bf16 (region 0) + 4 W transposes (regions 1-4) --
__global__ __launch_bounds__(256)
void prep(const float* __restrict__ x, const float* __restrict__ Wq,
          const float* __restrict__ Wk, const float* __restrict__ Wv,
          const float* __restrict__ Wo, unsigned short* __restrict__ Xb,
          unsigned short* __restrict__ WqkvT, unsigned short* __restrict__ WoT) {
  const int bid = blockIdx.x, t = threadIdx.x;
  if (bid < 512) {                              // ---- cast x: 8 bf16/thread/iter
    int idx = bid * 256 + t;
    for (; idx < 1048576; idx += 131072) {
      const float4* p = (const float4*)(x + (size_t)idx * 8);
      float4 v0 = p[0], v1 = p[1];
      bf16x8 o;
      o[0] = (short)f2bf(v0.x); o[1] = (short)f2bf(v0.y);
      o[2] = (short)f2bf(v0.z); o[3] = (short)f2bf(v0.w);
      o[4] = (short)f2bf(v1.x); o[5] = (short)f2bf(v1.y);
      o[6] = (short)f2bf(v1.z); o[7] = (short)f2bf(v1.w);
      *(bf16x8*)(Xb + (size_t)idx * 8) = o;
    }
    return;
  }
  const float* W;
  unsigned short* Wt;
  int n0, k0, Nw;
  if (bid < 4608)      { int b2 = bid - 512;  W = Wq; Wt = WqkvT;              Nw = 2048; n0 = (b2 & 63) * 32; k0 = (b2 >> 6) * 32; }
  else if (bid < 5632) { int b2 = bid - 4608; W = Wk; Wt = WqkvT + 2048 * 2048; Nw = 512;  n0 = (b2 & 15) * 32; k0 = (b2 >> 4) * 32; }
  else if (bid < 6656) { int b2 = bid - 5632; W = Wv; Wt = WqkvT + 2560 * 2048; Nw = 512;  n0 = (b2 & 15) * 32; k0 = (b2 >> 4) * 32; }
  else                 { int b2 = bid - 6656; W = Wo; Wt = WoT;                Nw = 2048; n0 = (b2 & 63) * 32; k0 = (b2 >> 6) * 32; }
  __shared__ float tile[32][33];
  const int tx = t & 31, ty = t >> 5;
#pragma unroll
  for (int r = ty; r < 32; r += 8)
    tile[r][tx] = W[(size_t)(k0 + r) * Nw + n0 + tx];
  __syncthreads();
#pragma unroll
  for (int r = ty; r < 32; r += 8)
    Wt[(size_t)(n0 + r) * 2048 + k0 + tx] = f2bf(tile[tx][r]);
}

// ---------------- GEMM (m97 structure, BK=64): A[M][K] x Bt[N][K] ------------
template <int EPI>
__global__ __launch_bounds__(256, 3)
void gemm_bt(const unsigned short* __restrict__ A, const unsigned short* __restrict__ Bt,
             int Kr, float* __restrict__ Cf, int Nr,
             unsigned short* __restrict__ Qn, unsigned short* __restrict__ Kn,
             unsigned short* __restrict__ Vt, float qscale) {
  __shared__ __align__(16) unsigned short lsA[128 * 64];   // 16 KB
  __shared__ __align__(16) unsigned short lsB[128 * 64];   // 16 KB
  const int t = threadIdx.x;
  const int lane = t & 63;
  const int w = t >> 6, wr = w >> 1, wc = w & 1;
  const int lo = lane & 15, hi = lane >> 4;
  const int swz = lo & 7;
  const int nwg = gridDim.x * 32;
  const int bid0 = blockIdx.y * gridDim.x + blockIdx.x;
  const int sw = (bid0 & 7) * (nwg >> 3) + (bid0 >> 3);
  const int m0 = (sw & 31) * 128, n0 = (sw >> 5) * 128;

  f32x4 acc[4][4] = {};

  for (int kt = 0; kt < Kr; kt += 64) {
#pragma unroll
    for (int j = 0; j < 4; ++j) {
      int gi = j * 256 + t;
      int rw = gi >> 3, g = (gi & 7) ^ (rw & 7);
      async16(lsA + gi * 8, A + (size_t)(m0 + rw) * Kr + kt + g * 8);
      async16(lsB + gi * 8, Bt + (size_t)(n0 + rw) * Kr + kt + g * 8);
    }
    __syncthreads();
#pragma unroll
    for (int kk = 0; kk < 2; ++kk) {
      bf16x8 af[4], bfr[4];
#pragma unroll
      for (int i = 0; i < 4; ++i) {
        af[i]  = *(const bf16x8*)&lsA[(wr * 64 + i * 16 + lo) * 64 + (((kk * 4 + hi) ^ swz) << 3)];
        bfr[i] = *(const bf16x8*)&lsB[(wc * 64 + i * 16 + lo) * 64 + (((kk * 4 + hi) ^ swz) << 3)];
      }
#pragma unroll
      for (int mi = 0; mi < 4; ++mi)
#pragma unroll
        for (int ni = 0; ni < 4; ++ni)
          acc[mi][ni] = __builtin_amdgcn_mfma_f32_16x16x32_bf16(af[mi], bfr[ni], acc[mi][ni], 0, 0, 0);
    }
    __syncthreads();
  }

  float rr[4][4];
  if (EPI == 1 && n0 < 2560) {
    const float scl = (n0 < 2048) ? qscale : 1.0f;
    float p[4][4];
#pragma unroll
    for (int mi = 0; mi < 4; ++mi)
#pragma unroll
      for (int i = 0; i < 4; ++i) {
        float s = 0.f;
#pragma unroll
        for (int ni = 0; ni < 4; ++ni) s += acc[mi][ni][i] * acc[mi][ni][i];
        p[mi][i] = s;
      }
#pragma unroll
    for (int off = 1; off < 16; off <<= 1)
#pragma unroll
      for (int mi = 0; mi < 4; ++mi)
#pragma unroll
        for (int i = 0; i < 4; ++i) p[mi][i] += __shfl_xor(p[mi][i], off, 64);
    float* red = (float*)lsA;
    if (lo == 0)
#pragma unroll
      for (int mi = 0; mi < 4; ++mi)
#pragma unroll
        for (int i = 0; i < 4; ++i)
          red[(wr * 2 + wc) * 64 + mi * 16 + hi * 4 + i] = p[mi][i];
    __syncthreads();
#pragma unroll
    for (int mi = 0; mi < 4; ++mi)
#pragma unroll
      for (int i = 0; i < 4; ++i) {
        float tot = p[mi][i] + red[(wr * 2 + (wc ^ 1)) * 64 + mi * 16 + hi * 4 + i];
        rr[mi][i] = rsqrtf(tot * (1.0f / 128.0f) + 1e-6f) * scl;
      }
  }

#pragma unroll
  for (int mi = 0; mi < 4; ++mi)
#pragma unroll
    for (int ni = 0; ni < 4; ++ni)
#pragma unroll
      for (int i = 0; i < 4; ++i) {
        int gm = m0 + wr * 64 + mi * 16 + hi * 4 + i;
        int gn = n0 + wc * 64 + ni * 16 + lo;
        float v = acc[mi][ni][i];
        if (EPI == 0) {
          Cf[(size_t)gm * Nr + gn] = v;
        } else {
          if (n0 < 2560) v *= rr[mi][i];
          unsigned short bv = f2bf(v);
          int bb = gm >> 11, tt = gm & 2047;
          if (gn < 2048) {
            int hh = gn >> 7, dd = gn & 127;
            Qn[(((size_t)bb * 16 + hh) * 2048 + tt) * 128 + dd] = bv;
          } else if (gn < 2560) {
            int g2 = gn - 2048, hh = g2 >> 7, dd = g2 & 127;
            Kn[(((size_t)bb * 4 + hh) * 2048 + tt) * 128 + dd] = bv;
          } else {
            int g2 = gn - 2560, hh = g2 >> 7, dd = g2 & 127;
            Vt[(((size_t)bb * 4 + hh) * 128 + dd) * 2048 + tt] = bv;
          }
        }
      }
}

// ---------------- fragmentize V into MFMA-consumption order (r8/r10-verified) --
__global__ __launch_bounds__(256)
void fragV(const unsigned short* __restrict__ Vt, unsigned short* __restrict__ Vf) {
  int tid = blockIdx.x * 256 + threadIdx.x;      // 262144 threads
  int bhkv = tid >> 15, c = tid & 32767;
  int lane = c & 63, tile = c >> 10, mid = (c >> 6) & 15;
  int dt = mid >> 2, g2 = mid & 3;
  int d = dt * 32 + (lane & 31);
  int g = g2 * 2 + (lane >> 5);
  int k0 = tile * 64 + g * 8;
  const uint4* src = (const uint4*)(Vt + ((size_t)bhkv * 128 + d) * 2048 + k0);
  uint4* dst = (uint4*)(Vf + (size_t)bhkv * 262144 + (size_t)c * 8);
  *dst = *src;
}

// ======== full-KV attention (r14-verified fallback path) =======================
__global__ __launch_bounds__(256, 2)
void attn(const unsigned short* __restrict__ Q, const unsigned short* __restrict__ Kk,
          const unsigned short* __restrict__ Vt, unsigned short* __restrict__ AO) {
  const int bid = blockIdx.x;
  const int bh = (bid & 7) + 8 * (bid >> 7);
  const int qx = (bid >> 3) & 15;
  const int b = bh >> 4, h = bh & 15;
  const int hkv = h >> 2;
  const int t = threadIdx.x;
  const int w = t >> 6, lane = t & 63;
  const int qi = lane & 31, h1 = lane >> 5;
  const unsigned short* Qb = Q  + (size_t)bh * 2048 * 128;
  const unsigned short* Kb = Kk + (size_t)(b * 4 + hkv) * 2048 * 128;
  const unsigned short* Vb = Vt + (size_t)(b * 4 + hkv) * 128 * 2048;
  const int q0 = qx * 128 + w * 32;

  __shared__ __align__(16) unsigned short Klds[2][64 * 128];
  __shared__ __align__(16) unsigned short Vlds[2][128 * 64];

  bf16x8 qf[8];
#pragma unroll
  for (int s = 0; s < 8; ++s)
    qf[s] = *(const bf16x8*)&Qb[(size_t)(q0 + qi) * 128 + s * 16 + h1 * 8];

  f32x16 Oc[4] = {};
  float mrow = -1e30f, srow = 0.f;

#define STAGE_KV(bufi, kt_)                                                      \
  {                                                                              \
    const unsigned short* gK = Kb + (size_t)(kt_) * 128;                         \
    const unsigned short* gV = Vb + (kt_);                                       \
    _Pragma("unroll")                                                            \
    for (int j = 0; j < 4; ++j) {                                                \
      int gi = j * 256 + t;                                                      \
      int kr = gi >> 4, kg = (gi & 15) ^ (kr & 15);                              \
      async16(&Klds[bufi][gi * 8], gK + (size_t)kr * 128 + kg * 8);              \
      int vr = gi >> 3, vg = (gi & 7) ^ (vr & 7);                                \
      async16(&Vlds[bufi][gi * 8], gV + (size_t)vr * 2048 + vg * 8);             \
    }                                                                            \
  }

  STAGE_KV(0, 0);
  __syncthreads();

  int cur = 0;
  for (int kt = 0; kt < 2048; kt += 64) {
    if (kt + 64 < 2048) STAGE_KV(cur ^ 1, kt + 64);

    const unsigned short* KL = Klds[cur];
    const unsigned short* VL = Vlds[cur];

    f32x16 S[2] = {};
    __builtin_amdgcn_s_setprio(1);
#pragma unroll
    for (int mt = 0; mt < 2; ++mt) {
      const int krow = mt * 32 + qi;
      const unsigned short* krp = KL + krow * 128;
      const int rswz = krow & 15;
#pragma unroll
      for (int s = 0; s < 8; ++s) {
        bf16x8 kf = *(const bf16x8*)(krp + (((2 * s + h1) ^ rswz) << 3));
        S[mt] = __builtin_amdgcn_mfma_f32_32x32x16_bf16(kf, qf[s], S[mt], 0, 0, 0);
      }
    }
    __builtin_amdgcn_s_setprio(0);

    float t8[8];
#pragma unroll
    for (int r = 0; r < 8; ++r)
      t8[r] = fmaxf(fmaxf(S[0][r], S[0][r + 8]), fmaxf(S[1][r], S[1][r + 8]));
#pragma unroll
    for (int r = 0; r < 4; ++r) t8[r] = fmaxf(t8[r], t8[r + 4]);
    float mx = fmaxf(fmaxf(t8[0], t8[1]), fmaxf(t8[2], t8[3]));
    mx = fmaxf(mx, __shfl_xor(mx, 32, 64));
    if (__any(mx > mrow + 8.0f)) {
      float mnew = fmaxf(mrow, mx);
      float al = __builtin_amdgcn_exp2f(mrow - mnew);
      mrow = mnew;
      srow *= al;
#pragma unroll
      for (int dt = 0; dt < 4; ++dt)
#pragma unroll
        for (int r = 0; r < 16; ++r) Oc[dt][r] *= al;
    }
#pragma unroll
    for (int mt = 0; mt < 2; ++mt)
#pragma unroll
      for (int r = 0; r < 16; ++r)
        S[mt][r] = __builtin_amdgcn_exp2f(S[mt][r] - mrow);
    float s8[8];
#pragma unroll
    for (int r = 0; r < 8; ++r)
      s8[r] = (S[0][r] + S[0][r + 8]) + (S[1][r] + S[1][r + 8]);
#pragma unroll
    for (int r = 0; r < 4; ++r) s8[r] += s8[r + 4];
    float rs = (s8[0] + s8[1]) + (s8[2] + s8[3]);
    rs += __shfl_xor(rs, 32, 64);
    srow += rs;

    __builtin_amdgcn_s_setprio(1);
#pragma unroll
    for (int mt = 0; mt < 2; ++mt) {
      unsigned wd[8];
#pragma unroll
      for (int i2 = 0; i2 < 8; ++i2) wd[i2] = cvtpk(S[mt][2 * i2], S[mt][2 * i2 + 1]);
      unsigned r0 = __shfl_xor(h1 ? wd[0] : wd[2], 32, 64);
      unsigned r1 = __shfl_xor(h1 ? wd[1] : wd[3], 32, 64);
      unsigned r2 = __shfl_xor(h1 ? wd[4] : wd[6], 32, 64);
      unsigned r3 = __shfl_xor(h1 ? wd[5] : wd[7], 32, 64);
      bf16x8 pf0 = frag4(h1 ? r0 : wd[0], h1 ? r1 : wd[1], h1 ? wd[2] : r0, h1 ? wd[3] : r1);
      bf16x8 pf1 = frag4(h1 ? r2 : wd[4], h1 ? r3 : wd[5], h1 ? wd[6] : r2, h1 ? wd[7] : r3);
#pragma unroll
      for (int dt = 0; dt < 4; ++dt) {
        const int vrow = dt * 32 + qi;
        const unsigned short* vrp = VL + vrow * 64;
        const int vswz = vrow & 7;
        bf16x8 v0 = *(const bf16x8*)(vrp + (((mt * 4 + 0 + h1) ^ vswz) << 3));
        bf16x8 v1 = *(const bf16x8*)(vrp + (((mt * 4 + 2 + h1) ^ vswz) << 3));
        Oc[dt] = __builtin_amdgcn_mfma_f32_32x32x16_bf16(v0, pf0, Oc[dt], 0, 0, 0);
        Oc[dt] = __builtin_amdgcn_mfma_f32_32x32x16_bf16(v1, pf1, Oc[dt], 0, 0, 0);
      }
    }
    __builtin_amdgcn_s_setprio(0);

    __syncthreads();
    cur ^= 1;
  }

  const float inv = 1.0f / srow;
  const size_t orow = ((size_t)(b * 2048 + q0 + qi)) * 2048 + h * 128;
#pragma unroll
  for (int dt = 0; dt < 4; ++dt)
#pragma unroll
    for (int rq = 0; rq < 4; ++rq) {
      int d0 = dt * 32 + 8 * rq + 4 * h1;
      unsigned u0 = cvtpk(Oc[dt][4 * rq + 0] * inv, Oc[dt][4 * rq + 1] * inv);
      unsigned u1 = cvtpk(Oc[dt][4 * rq + 2] * inv, Oc[dt][4 * rq + 3] * inv);
      uint2 st = {u0, u1};
      *(uint2*)((unsigned short*)AO + orow + d0) = st;
    }
}

// ======== KV-split attention, register-trimmed for 3 blocks/CU ================
// V frags loaded per-mt (8 live, 32 VGPR) instead of 16 upfront; (256,3) caps
// arch VGPR ~104 (quota 170 - 64 AGPR) so 3 blocks x 4 waves = 12 waves/CU.
__global__ __launch_bounds__(256, 3)
void attn_split(const unsigned short* __restrict__ Q, const unsigned short* __restrict__ Kk,
                const unsigned short* __restrict__ Vf, unsigned short* __restrict__ pA,
                unsigned short* __restrict__ pB, float* __restrict__ ms) {
  const int bid = blockIdx.x;                 // 1024 = 8(xcd) x 2(half) x 4(h2) x 16(qx)
  const int x = bid & 7, r = bid >> 3;
  const int half = r & 1, h2 = (r >> 1) & 3, qx = r >> 3;
  const int b = x >> 2, hkv = x & 3;
  const int h = hkv * 4 + h2, bh = b * 16 + h, bhkv = b * 4 + hkv;
  const int t = threadIdx.x;
  const int w = t >> 6, lane = t & 63;
  const int qi = lane & 31, h1 = lane >> 5;
  const unsigned short* Qb = Q  + (size_t)bh * 2048 * 128;
  const unsigned short* Kb = Kk + (size_t)bhkv * 2048 * 128;
  const unsigned short* Vfb = Vf + (size_t)bhkv * 262144;
  const int q0 = qx * 128 + w * 32;
  const int t0 = half * 16, t1 = t0 + 16;     // 64-key tiles [t0, t1)

  __shared__ __align__(16) unsigned short Klds[2][64 * 128];  // 32 KB

  bf16x8 qf[8];
#pragma unroll
  for (int s = 0; s < 8; ++s)
    qf[s] = *(const bf16x8*)&Qb[(size_t)(q0 + qi) * 128 + s * 16 + h1 * 8];

  f32x16 Oc[4] = {};
  float mrow = -1e30f, srow = 0.f;

#define STAGE_K2(bufi, kt_)                                                      \
  {                                                                              \
    const unsigned short* gK = Kb + (size_t)(kt_) * 128;                         \
    _Pragma("unroll")                                                            \
    for (int j = 0; j < 4; ++j) {                                                \
      int gi = j * 256 + t;                                                      \
      int kr = gi >> 4, kg = (gi & 15) ^ (kr & 15);                              \
      async16(&Klds[bufi][gi * 8], gK + (size_t)kr * 128 + kg * 8);              \
    }                                                                            \
  }

  STAGE_K2(0, t0 * 64);
  __syncthreads();

  int cur = 0;
  for (int ti = t0; ti < t1; ++ti) {
    if (ti + 1 < t1) STAGE_K2(cur ^ 1, (ti + 1) * 64);

    const unsigned short* KL = Klds[cur];

    // ---- QK^T (swapped) ----
    f32x16 S[2] = {};
    __builtin_amdgcn_s_setprio(1);
#pragma unroll
    for (int mt = 0; mt < 2; ++mt) {
      const int krow = mt * 32 + qi;
      const unsigned short* krp = KL + krow * 128;
      const int rswz = krow & 15;
#pragma unroll
      for (int s = 0; s < 8; ++s) {
        bf16x8 kf = *(const bf16x8*)(krp + (((2 * s + h1) ^ rswz) << 3));
        S[mt] = __builtin_amdgcn_mfma_f32_32x32x16_bf16(kf, qf[s], S[mt], 0, 0, 0);
      }
    }
    __builtin_amdgcn_s_setprio(0);

    // ---- online softmax (base-2), tree reductions ----
    float t8[8];
#pragma unroll
    for (int r2 = 0; r2 < 8; ++r2)
      t8[r2] = fmaxf(fmaxf(S[0][r2], S[0][r2 + 8]), fmaxf(S[1][r2], S[1][r2 + 8]));
#pragma unroll
    for (int r2 = 0; r2 < 4; ++r2) t8[r2] = fmaxf(t8[r2], t8[r2 + 4]);
    float mx = fmaxf(fmaxf(t8[0], t8[1]), fmaxf(t8[2], t8[3]));
    mx = fmaxf(mx, __shfl_xor(mx, 32, 64));
    if (__any(mx > mrow + 8.0f)) {
      float mnew = fmaxf(mrow, mx);
      float al = __builtin_amdgcn_exp2f(mrow - mnew);
      mrow = mnew;
      srow *= al;
#pragma unroll
      for (int dt = 0; dt < 4; ++dt)
#pragma unroll
        for (int r2 = 0; r2 < 16; ++r2) Oc[dt][r2] *= al;
    }
#pragma unroll
    for (int mt = 0; mt < 2; ++mt)
#pragma unroll
      for (int r2 = 0; r2 < 16; ++r2)
        S[mt][r2] = __builtin_amdgcn_exp2f(S[mt][r2] - mrow);
    float s8[8];
#pragma unroll
    for (int r2 = 0; r2 < 8; ++r2)
      s8[r2] = (S[0][r2] + S[0][r2 + 8]) + (S[1][r2] + S[1][r2 + 8]);
#pragma unroll
    for (int r2 = 0; r2 < 4; ++r2) s8[r2] += s8[r2 + 4];
    float rs = (s8[0] + s8[1]) + (s8[2] + s8[3]);
    rs += __shfl_xor(rs, 32, 64);
    srow += rs;

    // ---- P -> bf16 + PV; V frags loaded per-mt (register-trimmed) ----
    bf16x8 vf0[4], vf1[4];
#pragma unroll
    for (int mt = 0; mt < 2; ++mt) {
      if (mt == 1) __builtin_amdgcn_sched_barrier(0);  // pin reload after PV(mt=0)
#pragma unroll
      for (int dt = 0; dt < 4; ++dt) {
        const unsigned short* vp = Vfb + ((size_t)((ti * 4 + dt) * 4 + mt * 2)) * 512 + lane * 8;
        vf0[dt] = *(const bf16x8*)(vp);
        vf1[dt] = *(const bf16x8*)(vp + 512);
      }
      unsigned wd[8];
#pragma unroll
      for (int i2 = 0; i2 < 8; ++i2) wd[i2] = cvtpk(S[mt][2 * i2], S[mt][2 * i2 + 1]);
      unsigned r0 = __shfl_xor(h1 ? wd[0] : wd[2], 32, 64);
      unsigned r1 = __shfl_xor(h1 ? wd[1] : wd[3], 32, 64);
      unsigned r2_ = __shfl_xor(h1 ? wd[4] : wd[6], 32, 64);
      unsigned r3 = __shfl_xor(h1 ? wd[5] : wd[7], 32, 64);
      bf16x8 pf0 = frag4(h1 ? r0 : wd[0], h1 ? r1 : wd[1], h1 ? wd[2] : r0, h1 ? wd[3] : r1);
      bf16x8 pf1 = frag4(h1 ? r2_ : wd[4], h1 ? r3 : wd[5], h1 ? wd[6] : r2_, h1 ? wd[7] : r3);
      __builtin_amdgcn_s_setprio(1);
#pragma unroll
      for (int dt = 0; dt < 4; ++dt) {
        Oc[dt] = __builtin_amdgcn_mfma_f32_32x32x16_bf16(vf0[dt], pf0, Oc[dt], 0, 0, 0);
        Oc[dt] = __builtin_amdgcn_mfma_f32_32x32x16_bf16(vf1[dt], pf1, Oc[dt], 0, 0, 0);
      }
      __builtin_amdgcn_s_setprio(0);
    }

    __syncthreads();
    cur ^= 1;
  }

  // ---- epilogue: partial O (normalized) + per-row (m, s) ----
  unsigned short* dst = half ? pB : pA;
  const float inv = 1.0f / srow;
  const size_t orow = ((size_t)(b * 2048 + q0 + qi)) * 2048 + h * 128;
#pragma unroll
  for (int dt = 0; dt < 4; ++dt)
#pragma unroll
    for (int rq = 0; rq < 4; ++rq) {
      int d0 = dt * 32 + 8 * rq + 4 * h1;
      unsigned u0 = cvtpk(Oc[dt][4 * rq + 0] * inv, Oc[dt][4 * rq + 1] * inv);
      unsigned u1 = cvtpk(Oc[dt][4 * rq + 2] * inv, Oc[dt][4 * rq + 3] * inv);
      uint2 st = {u0, u1};
      *(uint2*)(dst + orow + d0) = st;
    }
  if (h1 == 0) {
    int rowg = (bh << 11) + q0 + qi;            // bh*2048 + t
    ms[((size_t)half * 65536 + rowg) * 2 + 0] = mrow;
    ms[((size_t)half * 65536 + rowg) * 2 + 1] = srow;
  }
}

// ---- flash-combine: AO = (wa*pA + wb*pB), wa/wb from per-row (m,s) ------------
__global__ __launch_bounds__(256)
void combine(unsigned short* __restrict__ pA, const unsigned short* __restrict__ pB,
             const float* __restrict__ ms) {
  int tid = blockIdx.x * 256 + threadIdx.x;     // 1048576 threads
  int r2 = tid >> 8;                            // (b,t) row in [0,4096)
  int rest = tid & 255;
  int h = rest >> 4, c8 = rest & 15;
  int bb = r2 >> 11, tt = r2 & 2047;
  int rowm = ((bb * 16 + h) << 11) + tt;        // bh*2048 + t
  float ma = ms[(size_t)rowm * 2 + 0], sa = ms[(size_t)rowm * 2 + 1];
  float mb = ms[((size_t)65536 + rowm) * 2 + 0], sb = ms[((size_t)65536 + rowm) * 2 + 1];
  float M = fmaxf(ma, mb);
  float wa = sa * __builtin_amdgcn_exp2f(ma - M);
  float wb = sb * __builtin_amdgcn_exp2f(mb - M);
  float inv = 1.0f / (wa + wb);
  wa *= inv; wb *= inv;
  size_t addr = (size_t)r2 * 2048 + h * 128 + c8 * 8;
  bf16x8 a = *(const bf16x8*)(pA + addr);
  bf16x8 b = *(const bf16x8*)(pB + addr);
  unsigned o[4];
#pragma unroll
  for (int i = 0; i < 4; ++i) {
    float f0 = wa * bf2f((unsigned short)a[2 * i])     + wb * bf2f((unsigned short)b[2 * i]);
    float f1 = wa * bf2f((unsigned short)a[2 * i + 1]) + wb * bf2f((unsigned short)b[2 * i + 1]);
    o[i] = cvtpk(f0, f1);
  }
  u32x4 ov = {o[0], o[1], o[2], o[3]};
  *(u32x4*)(pA + addr) = ov;
}

// ------------------------------- launcher -------------------------------------
extern "C" void kernel_launch(void* const* d_in, const int* in_sizes, int n_in,
                              void* d_out, int out_size, void* d_ws, size_t ws_size,
                              hipStream_t stream) {
  const float* x_q = (const float*)d_in[0];
  const float* Wq  = (const float*)d_in[1];
  const float* Wk  = (const float*)d_in[2];
  const float* Wv  = (const float*)d_in[3];
  const float* Wo  = (const float*)d_in[4];
  float* out = (float*)d_out;

  char* ws = (char*)d_ws;
  unsigned short* Xb    = (unsigned short*)(ws);             // 16.8 MB (reused as AO/pA)
  unsigned short* WqkvT = (unsigned short*)(ws + 16777216);  // 12.6 MB (reused as Vf)
  unsigned short* WoT   = (unsigned short*)(ws + 29360128);  //  8.4 MB
  unsigned short* Qn    = (unsigned short*)(ws + 37748736);  // 16.8 MB
  unsigned short* Kn    = (unsigned short*)(ws + 54525952);  //  4.2 MB
  unsigned short* Vt    = (unsigned short*)(ws + 58720256);  //  4.2 MB
  unsigned short* AO    = Xb;
  unsigned short* Vf    = WqkvT;                             // 4.2 MB (after gemm1)
  unsigned short* pB    = (unsigned short*)(ws + 62914560);  // 16.8 MB (split path)
  float*          ms    = (float*)(ws + 79691776);           //  1.0 MB (split path)
  const bool split = ws_size >= 80740352ull;

  prep<<<10752, 256, 0, stream>>>(x_q, Wq, Wk, Wv, Wo, Xb, WqkvT, WoT);
  gemm_bt<1><<<dim3(3072 / 128, 4096 / 128), 256, 0, stream>>>(Xb, WqkvT, 2048, nullptr, 0,
                                                               Qn, Kn, Vt, 0.12751742f);
  if (split) {
    fragV<<<1024, 256, 0, stream>>>(Vt, Vf);
    attn_split<<<1024, 256, 0, stream>>>(Qn, Kn, Vf, AO, pB, ms);
    combine<<<4096, 256, 0, stream>>>(AO, pB, ms);
  } else {
    attn<<<512, 256, 0, stream>>>(Qn, Kn, Vt, AO);
  }
  gemm_bt<0><<<dim3(2048 / 128, 4096 / 128), 256, 0, stream>>>(AO, WoT, 2048, out, 2048,
                                                               nullptr, nullptr, nullptr, 0.f);
}

// Round 19
// 213.967 us; speedup vs baseline: 1.3981x; 1.3981x over previous
//
#include <hip/hip_runtime.h>

typedef __attribute__((ext_vector_type(4))) float f32x4;
typedef __attribute__((ext_vector_type(16))) float f32x16;
typedef __attribute__((ext_vector_type(8))) short bf16x8;
typedef __attribute__((ext_vector_type(4))) unsigned u32x4;

#define DEV __device__ __forceinline__

DEV unsigned short f2bf(float f) {            // RTNE f32 -> bf16
  unsigned u = __float_as_uint(f);
  unsigned r = (u + 0x7FFFu + ((u >> 16) & 1u)) >> 16;
  return (unsigned short)r;
}
DEV float bf2f(unsigned short h) { return __uint_as_float(((unsigned)h) << 16); }

DEV unsigned cvtpk(float lo, float hi) {      // packed f32x2 -> bf16x2 (HW RTNE)
  unsigned r;
  asm("v_cvt_pk_bf16_f32 %0, %1, %2" : "=v"(r) : "v"(lo), "v"(hi));
  return r;
}
DEV bf16x8 frag4(unsigned a, unsigned b, unsigned c, unsigned d) {
  u32x4 u = {a, b, c, d};
  return __builtin_bit_cast(bf16x8, u);
}

typedef __attribute__((address_space(1))) void gas_t;
typedef __attribute__((address_space(3))) void las_t;
DEV void async16(void* lds, const void* g) {
  __builtin_amdgcn_global_load_lds((gas_t*)g, (las_t*)lds, 16, 0, 0);
}

// ------- fused prep: cast x -> bf16 (region 0) + 4 W transposes (regions 1-4) --
__global__ __launch_bounds__(256)
void prep(const float* __restrict__ x, const float* __restrict__ Wq,
          const float* __restrict__ Wk, const float* __restrict__ Wv,
          const float* __restrict__ Wo, unsigned short* __restrict__ Xb,
          unsigned short* __restrict__ WqkvT, unsigned short* __restrict__ WoT) {
  const int bid = blockIdx.x, t = threadIdx.x;
  if (bid < 512) {                              // ---- cast x: 8 bf16/thread/iter
    int idx = bid * 256 + t;
    for (; idx < 1048576; idx += 131072) {
      const float4* p = (const float4*)(x + (size_t)idx * 8);
      float4 v0 = p[0], v1 = p[1];
      bf16x8 o;
      o[0] = (short)f2bf(v0.x); o[1] = (short)f2bf(v0.y);
      o[2] = (short)f2bf(v0.z); o[3] = (short)f2bf(v0.w);
      o[4] = (short)f2bf(v1.x); o[5] = (short)f2bf(v1.y);
      o[6] = (short)f2bf(v1.z); o[7] = (short)f2bf(v1.w);
      *(bf16x8*)(Xb + (size_t)idx * 8) = o;
    }
    return;
  }
  const float* W;
  unsigned short* Wt;
  int n0, k0, Nw;
  if (bid < 4608)      { int b2 = bid - 512;  W = Wq; Wt = WqkvT;              Nw = 2048; n0 = (b2 & 63) * 32; k0 = (b2 >> 6) * 32; }
  else if (bid < 5632) { int b2 = bid - 4608; W = Wk; Wt = WqkvT + 2048 * 2048; Nw = 512;  n0 = (b2 & 15) * 32; k0 = (b2 >> 4) * 32; }
  else if (bid < 6656) { int b2 = bid - 5632; W = Wv; Wt = WqkvT + 2560 * 2048; Nw = 512;  n0 = (b2 & 15) * 32; k0 = (b2 >> 4) * 32; }
  else                 { int b2 = bid - 6656; W = Wo; Wt = WoT;                Nw = 2048; n0 = (b2 & 63) * 32; k0 = (b2 >> 6) * 32; }
  __shared__ float tile[32][33];
  const int tx = t & 31, ty = t >> 5;
#pragma unroll
  for (int r = ty; r < 32; r += 8)
    tile[r][tx] = W[(size_t)(k0 + r) * Nw + n0 + tx];
  __syncthreads();
#pragma unroll
  for (int r = ty; r < 32; r += 8)
    Wt[(size_t)(n0 + r) * 2048 + k0 + tx] = f2bf(tile[tx][r]);
}

// ---------------- GEMM (m97 structure, BK=64): A[M][K] x Bt[N][K] ------------
template <int EPI>
__global__ __launch_bounds__(256, 3)
void gemm_bt(const unsigned short* __restrict__ A, const unsigned short* __restrict__ Bt,
             int Kr, float* __restrict__ Cf, int Nr,
             unsigned short* __restrict__ Qn, unsigned short* __restrict__ Kn,
             unsigned short* __restrict__ Vt, float qscale) {
  __shared__ __align__(16) unsigned short lsA[128 * 64];   // 16 KB
  __shared__ __align__(16) unsigned short lsB[128 * 64];   // 16 KB
  const int t = threadIdx.x;
  const int lane = t & 63;
  const int w = t >> 6, wr = w >> 1, wc = w & 1;
  const int lo = lane & 15, hi = lane >> 4;
  const int swz = lo & 7;
  const int nwg = gridDim.x * 32;
  const int bid0 = blockIdx.y * gridDim.x + blockIdx.x;
  const int sw = (bid0 & 7) * (nwg >> 3) + (bid0 >> 3);
  const int m0 = (sw & 31) * 128, n0 = (sw >> 5) * 128;

  f32x4 acc[4][4] = {};

  for (int kt = 0; kt < Kr; kt += 64) {
#pragma unroll
    for (int j = 0; j < 4; ++j) {
      int gi = j * 256 + t;
      int rw = gi >> 3, g = (gi & 7) ^ (rw & 7);
      async16(lsA + gi * 8, A + (size_t)(m0 + rw) * Kr + kt + g * 8);
      async16(lsB + gi * 8, Bt + (size_t)(n0 + rw) * Kr + kt + g * 8);
    }
    __syncthreads();
#pragma unroll
    for (int kk = 0; kk < 2; ++kk) {
      bf16x8 af[4], bfr[4];
#pragma unroll
      for (int i = 0; i < 4; ++i) {
        af[i]  = *(const bf16x8*)&lsA[(wr * 64 + i * 16 + lo) * 64 + (((kk * 4 + hi) ^ swz) << 3)];
        bfr[i] = *(const bf16x8*)&lsB[(wc * 64 + i * 16 + lo) * 64 + (((kk * 4 + hi) ^ swz) << 3)];
      }
#pragma unroll
      for (int mi = 0; mi < 4; ++mi)
#pragma unroll
        for (int ni = 0; ni < 4; ++ni)
          acc[mi][ni] = __builtin_amdgcn_mfma_f32_16x16x32_bf16(af[mi], bfr[ni], acc[mi][ni], 0, 0, 0);
    }
    __syncthreads();
  }

  float rr[4][4];
  if (EPI == 1 && n0 < 2560) {
    const float scl = (n0 < 2048) ? qscale : 1.0f;
    float p[4][4];
#pragma unroll
    for (int mi = 0; mi < 4; ++mi)
#pragma unroll
      for (int i = 0; i < 4; ++i) {
        float s = 0.f;
#pragma unroll
        for (int ni = 0; ni < 4; ++ni) s += acc[mi][ni][i] * acc[mi][ni][i];
        p[mi][i] = s;
      }
#pragma unroll
    for (int off = 1; off < 16; off <<= 1)
#pragma unroll
      for (int mi = 0; mi < 4; ++mi)
#pragma unroll
        for (int i = 0; i < 4; ++i) p[mi][i] += __shfl_xor(p[mi][i], off, 64);
    float* red = (float*)lsA;
    if (lo == 0)
#pragma unroll
      for (int mi = 0; mi < 4; ++mi)
#pragma unroll
        for (int i = 0; i < 4; ++i)
          red[(wr * 2 + wc) * 64 + mi * 16 + hi * 4 + i] = p[mi][i];
    __syncthreads();
#pragma unroll
    for (int mi = 0; mi < 4; ++mi)
#pragma unroll
      for (int i = 0; i < 4; ++i) {
        float tot = p[mi][i] + red[(wr * 2 + (wc ^ 1)) * 64 + mi * 16 + hi * 4 + i];
        rr[mi][i] = rsqrtf(tot * (1.0f / 128.0f) + 1e-6f) * scl;
      }
  }

#pragma unroll
  for (int mi = 0; mi < 4; ++mi)
#pragma unroll
    for (int ni = 0; ni < 4; ++ni)
#pragma unroll
      for (int i = 0; i < 4; ++i) {
        int gm = m0 + wr * 64 + mi * 16 + hi * 4 + i;
        int gn = n0 + wc * 64 + ni * 16 + lo;
        float v = acc[mi][ni][i];
        if (EPI == 0) {
          Cf[(size_t)gm * Nr + gn] = v;
        } else {
          if (n0 < 2560) v *= rr[mi][i];
          unsigned short bv = f2bf(v);
          int bb = gm >> 11, tt = gm & 2047;
          if (gn < 2048) {
            int hh = gn >> 7, dd = gn & 127;
            Qn[(((size_t)bb * 16 + hh) * 2048 + tt) * 128 + dd] = bv;
          } else if (gn < 2560) {
            int g2 = gn - 2048, hh = g2 >> 7, dd = g2 & 127;
            Kn[(((size_t)bb * 4 + hh) * 2048 + tt) * 128 + dd] = bv;
          } else {
            int g2 = gn - 2560, hh = g2 >> 7, dd = g2 & 127;
            Vt[(((size_t)bb * 4 + hh) * 128 + dd) * 2048 + tt] = bv;
          }
        }
      }
}

// ---------------- flash attention: swapped-QK^T 32x32 MFMA, in-register softmax
__global__ __launch_bounds__(256, 2)
void attn(const unsigned short* __restrict__ Q, const unsigned short* __restrict__ Kk,
          const unsigned short* __restrict__ Vt, unsigned short* __restrict__ AO) {
  const int bid = blockIdx.x;
  const int bh = (bid & 7) + 8 * (bid >> 7);   // XCD swizzle (512 % 8 == 0, bijective)
  const int qx = (bid >> 3) & 15;
  const int b = bh >> 4, h = bh & 15;
  const int hkv = h >> 2;
  const int t = threadIdx.x;
  const int w = t >> 6, lane = t & 63;
  const int qi = lane & 31, h1 = lane >> 5;
  const unsigned short* Qb = Q  + (size_t)bh * 2048 * 128;
  const unsigned short* Kb = Kk + (size_t)(b * 4 + hkv) * 2048 * 128;
  const unsigned short* Vb = Vt + (size_t)(b * 4 + hkv) * 128 * 2048;
  const int q0 = qx * 128 + w * 32;

  __shared__ __align__(16) unsigned short Klds[2][64 * 128];  // 32 KB, granule^(row&15)
  __shared__ __align__(16) unsigned short Vlds[2][128 * 64];  // 32 KB, granule^(row&7)

  bf16x8 qf[8];
#pragma unroll
  for (int s = 0; s < 8; ++s)
    qf[s] = *(const bf16x8*)&Qb[(size_t)(q0 + qi) * 128 + s * 16 + h1 * 8];

  f32x16 Oc[4] = {};            // O^T acc: col=q (lane), row=d-offset
  float mrow = -1e30f, srow = 0.f;

#define STAGE_KV(bufi, kt_)                                                      \
  {                                                                              \
    const unsigned short* gK = Kb + (size_t)(kt_) * 128;                         \
    const unsigned short* gV = Vb + (kt_);                                       \
    _Pragma("unroll")                                                            \
    for (int j = 0; j < 4; ++j) {                                                \
      int gi = j * 256 + t;                                                      \
      int kr = gi >> 4, kg = (gi & 15) ^ (kr & 15);                              \
      async16(&Klds[bufi][gi * 8], gK + (size_t)kr * 128 + kg * 8);              \
      int vr = gi >> 3, vg = (gi & 7) ^ (vr & 7);                                \
      async16(&Vlds[bufi][gi * 8], gV + (size_t)vr * 2048 + vg * 8);             \
    }                                                                            \
  }

  STAGE_KV(0, 0);
  __syncthreads();

  int cur = 0;
  for (int kt = 0; kt < 2048; kt += 64) {
    if (kt + 64 < 2048) STAGE_KV(cur ^ 1, kt + 64);

    const unsigned short* KL = Klds[cur];
    const unsigned short* VL = Vlds[cur];

    // ---- QK^T (swapped): S[mt] = K_tile^T-frag x Q-frag; lane q = qi ----
    f32x16 S[2] = {};
    __builtin_amdgcn_s_setprio(1);
#pragma unroll
    for (int mt = 0; mt < 2; ++mt) {
      const int krow = mt * 32 + qi;
      const unsigned short* krp = KL + krow * 128;
      const int rswz = krow & 15;
#pragma unroll
      for (int s = 0; s < 8; ++s) {
        bf16x8 kf = *(const bf16x8*)(krp + (((2 * s + h1) ^ rswz) << 3));
        S[mt] = __builtin_amdgcn_mfma_f32_32x32x16_bf16(kf, qf[s], S[mt], 0, 0, 0);
      }
    }
    __builtin_amdgcn_s_setprio(0);
    // lane holds P[q=qi][key = mt*32 + (r&3) + 8*(r>>2) + 4*h1], r=0..15

    // ---- in-register online softmax (base-2), tree reductions ----
    float t8[8];
#pragma unroll
    for (int r = 0; r < 8; ++r)
      t8[r] = fmaxf(fmaxf(S[0][r], S[0][r + 8]), fmaxf(S[1][r], S[1][r + 8]));
#pragma unroll
    for (int r = 0; r < 4; ++r) t8[r] = fmaxf(t8[r], t8[r + 4]);
    float mx = fmaxf(fmaxf(t8[0], t8[1]), fmaxf(t8[2], t8[3]));
    mx = fmaxf(mx, __shfl_xor(mx, 32, 64));
    if (__any(mx > mrow + 8.0f)) {             // defer-max THR=8 (base-2)
      float mnew = fmaxf(mrow, mx);
      float al = __builtin_amdgcn_exp2f(mrow - mnew);
      mrow = mnew;
      srow *= al;
#pragma unroll
      for (int dt = 0; dt < 4; ++dt)
#pragma unroll
        for (int r = 0; r < 16; ++r) Oc[dt][r] *= al;
    }
#pragma unroll
    for (int mt = 0; mt < 2; ++mt)
#pragma unroll
      for (int r = 0; r < 16; ++r)
        S[mt][r] = __builtin_amdgcn_exp2f(S[mt][r] - mrow);
    float s8[8];
#pragma unroll
    for (int r = 0; r < 8; ++r)
      s8[r] = (S[0][r] + S[0][r + 8]) + (S[1][r] + S[1][r + 8]);
#pragma unroll
    for (int r = 0; r < 4; ++r) s8[r] += s8[r + 4];
    float rs = (s8[0] + s8[1]) + (s8[2] + s8[3]);
    rs += __shfl_xor(rs, 32, 64);
    srow += rs;

    // ---- P -> bf16 (HW cvt_pk), cross-half exchange, PV ----
    __builtin_amdgcn_s_setprio(1);
#pragma unroll
    for (int mt = 0; mt < 2; ++mt) {
      unsigned wd[8];
#pragma unroll
      for (int i2 = 0; i2 < 8; ++i2) wd[i2] = cvtpk(S[mt][2 * i2], S[mt][2 * i2 + 1]);
      unsigned r0 = __shfl_xor(h1 ? wd[0] : wd[2], 32, 64);
      unsigned r1 = __shfl_xor(h1 ? wd[1] : wd[3], 32, 64);
      unsigned r2 = __shfl_xor(h1 ? wd[4] : wd[6], 32, 64);
      unsigned r3 = __shfl_xor(h1 ? wd[5] : wd[7], 32, 64);
      bf16x8 pf0 = frag4(h1 ? r0 : wd[0], h1 ? r1 : wd[1], h1 ? wd[2] : r0, h1 ? wd[3] : r1);
      bf16x8 pf1 = frag4(h1 ? r2 : wd[4], h1 ? r3 : wd[5], h1 ? wd[6] : r2, h1 ? wd[7] : r3);
#pragma unroll
      for (int dt = 0; dt < 4; ++dt) {
        const int vrow = dt * 32 + qi;
        const unsigned short* vrp = VL + vrow * 64;
        const int vswz = vrow & 7;
        bf16x8 v0 = *(const bf16x8*)(vrp + (((mt * 4 + 0 + h1) ^ vswz) << 3));
        bf16x8 v1 = *(const bf16x8*)(vrp + (((mt * 4 + 2 + h1) ^ vswz) << 3));
        Oc[dt] = __builtin_amdgcn_mfma_f32_32x32x16_bf16(v0, pf0, Oc[dt], 0, 0, 0);
        Oc[dt] = __builtin_amdgcn_mfma_f32_32x32x16_bf16(v1, pf1, Oc[dt], 0, 0, 0);
      }
    }
    __builtin_amdgcn_s_setprio(0);

    __syncthreads();  // prefetch landed + all LDS reads done before overwrite
    cur ^= 1;
  }

  // ---- epilogue: O = Oc / srow; lane writes 32 d-values for its q row ----
  const float inv = 1.0f / srow;
  const size_t orow = ((size_t)(b * 2048 + q0 + qi)) * 2048 + h * 128;
#pragma unroll
  for (int dt = 0; dt < 4; ++dt)
#pragma unroll
    for (int rq = 0; rq < 4; ++rq) {
      int d0 = dt * 32 + 8 * rq + 4 * h1;
      unsigned u0 = cvtpk(Oc[dt][4 * rq + 0] * inv, Oc[dt][4 * rq + 1] * inv);
      unsigned u1 = cvtpk(Oc[dt][4 * rq + 2] * inv, Oc[dt][4 * rq + 3] * inv);
      uint2 st = {u0, u1};
      *(uint2*)((unsigned short*)AO + orow + d0) = st;
    }
}

// ------------------------------- launcher -------------------------------------
extern "C" void kernel_launch(void* const* d_in, const int* in_sizes, int n_in,
                              void* d_out, int out_size, void* d_ws, size_t ws_size,
                              hipStream_t stream) {
  const float* x_q = (const float*)d_in[0];
  const float* Wq  = (const float*)d_in[1];
  const float* Wk  = (const float*)d_in[2];
  const float* Wv  = (const float*)d_in[3];
  const float* Wo  = (const float*)d_in[4];
  float* out = (float*)d_out;

  char* ws = (char*)d_ws;
  unsigned short* Xb    = (unsigned short*)(ws);             // 16.8 MB (reused as AO)
  unsigned short* WqkvT = (unsigned short*)(ws + 16777216);  // 12.6 MB
  unsigned short* WoT   = (unsigned short*)(ws + 29360128);  //  8.4 MB
  unsigned short* Qn    = (unsigned short*)(ws + 37748736);  // 16.8 MB
  unsigned short* Kn    = (unsigned short*)(ws + 54525952);  //  4.2 MB
  unsigned short* Vt    = (unsigned short*)(ws + 58720256);  //  4.2 MB
  unsigned short* AO    = Xb;

  prep<<<10752, 256, 0, stream>>>(x_q, Wq, Wk, Wv, Wo, Xb, WqkvT, WoT);

  // Q scale = (1/sqrt(128)) * log2(e) -> softmax runs in base-2 (norm fused in epilogue)
  gemm_bt<1><<<dim3(3072 / 128, 4096 / 128), 256, 0, stream>>>(Xb, WqkvT, 2048, nullptr, 0,
                                                               Qn, Kn, Vt, 0.12751742f);
  attn<<<512, 256, 0, stream>>>(Qn, Kn, Vt, AO);
  gemm_bt<0><<<dim3(2048 / 128, 4096 / 128), 256, 0, stream>>>(AO, WoT, 2048, out, 2048,
                                                               nullptr, nullptr, nullptr, 0.f);
}